// Round 6
// baseline (238.467 us; speedup 1.0000x reference)
//
#include <hip/hip_runtime.h>
#include <hip/hip_bf16.h>

typedef short short8 __attribute__((ext_vector_type(8)));
typedef float f32x4 __attribute__((ext_vector_type(4)));
typedef unsigned uint4v __attribute__((ext_vector_type(4)));

#define F 32
#define NB 4
#define BINSH 5        // 32 nodes per bin
#define BINSZ 32
#define CAP 2048       // max edges classified per chunk (u16 indices)
#define SCH 8192       // edges per scatter block
#define MAXBIN 2048

__device__ __forceinline__ short f2bf(float f) {   // RNE f32->bf16
    unsigned u = __float_as_uint(f);
    unsigned r = (u + 0x7FFFu + ((u >> 16) & 1u)) >> 16;
    return (short)r;
}

__device__ __forceinline__ unsigned pk2(float a, float b) {  // packed bf16 pair
    __hip_bfloat162 h = __float22bfloat162_rn(make_float2(a, b));
    union { __hip_bfloat162 h; unsigned u; } cv; cv.h = h; return cv.u;
}

// ---------------- weight prep: bf16 B-fragment layout into ws --------------
__global__ __launch_bounds__(256) void w_prep(
    const float* __restrict__ w, short* __restrict__ wbf)
{
    int idx = blockIdx.x * 256 + threadIdx.x;   // 64 blocks x 256 = 16384
    int k = idx >> 10, rem = idx & 1023, i = rem >> 5, o = rem & 31;
    int slot = (((k * 4 + (i >> 3)) * 2 + (o >> 4)) * 16 + (o & 15)) * 8 + (i & 7);
    wbf[slot] = f2bf(w[idx]);
}

// ---------------- sort by dst-bin (block-local hist, cursor reservation) ----
__global__ __launch_bounds__(256) void k_hist(
    const int* __restrict__ ei, int E, int nbin, int* __restrict__ keycnt)
{
    __shared__ int h[MAXBIN];
    int t = threadIdx.x;
    for (int i = t; i < nbin; i += 256) h[i] = 0;
    __syncthreads();
    int stride = gridDim.x * blockDim.x;
    for (int e = blockIdx.x * blockDim.x + t; e < E; e += stride)
        atomicAdd(&h[ei[e] >> BINSH], 1);          // LDS atomic
    __syncthreads();
    for (int i = t; i < nbin; i += 256)
        if (h[i]) atomicAdd(&keycnt[i], h[i]);
}

__global__ __launch_bounds__(256) void k_scan(
    const int* __restrict__ keycnt, int* __restrict__ keybase,
    int* __restrict__ cursor, int nbin)
{
    __shared__ int part[256];
    int t = threadIdx.x;
    int chunk = (nbin + 255) / 256;
    int lo = t * chunk, hi = min(lo + chunk, nbin);
    int s = 0;
    for (int q = lo; q < hi; ++q) s += keycnt[q];
    part[t] = s;
    __syncthreads();
    if (t == 0) {
        int run = 0;
        for (int j = 0; j < 256; ++j) { int v = part[j]; part[j] = run; run += v; }
        keybase[nbin] = run;
    }
    __syncthreads();
    int run = part[t];
    for (int q = lo; q < hi; ++q) {
        keybase[q] = run; cursor[q] = run;
        run += keycnt[q];
    }
}

// rec.x = src(16) | dstloc(5)<<16 | cell(4)<<24 ; rec.y = qtx | qty<<16
__global__ __launch_bounds__(256) void k_scatter(
    const int* __restrict__ ei, const float* __restrict__ attr, int E, int nbin,
    int* __restrict__ cursor, uint2* __restrict__ packed)
{
    __shared__ int h[MAXBIN];
    int t = threadIdx.x, b = blockIdx.x;
    int start = b * SCH, end = min(start + SCH, E);
    for (int i = t; i < nbin; i += 256) h[i] = 0;
    __syncthreads();
    for (int e = start + t; e < end; e += 256)
        atomicAdd(&h[ei[e] >> BINSH], 1);
    __syncthreads();
    for (int k = t; k < nbin; k += 256) {
        int c = h[k];
        h[k] = c ? atomicAdd(&cursor[k], c) : 0;
    }
    __syncthreads();
    for (int e = start + t; e < end; e += 256) {
        int dst = ei[e];
        int src = ei[E + e];
        float2 a = reinterpret_cast<const float2*>(attr)[e];
        float tx = fminf(fmaxf((a.x + 1.0f) * 1.5f, 0.f), 3.f);
        float ty = fminf(fmaxf((a.y + 1.0f) * 1.5f, 0.f), 3.f);
        int kx = min((int)tx, 2), ky = min((int)ty, 2);
        unsigned qtx = (unsigned)(tx * 21845.0f + 0.5f);
        unsigned qty = (unsigned)(ty * 21845.0f + 0.5f);
        int key = dst >> BINSH;
        int pos = atomicAdd(&h[key], 1);
        uint2 rec;
        rec.x = (unsigned)src | ((unsigned)(dst & (BINSZ - 1)) << 16)
              | ((unsigned)(kx * 3 + ky) << 24);
        rec.y = qtx | (qty << 16);
        packed[pos] = rec;
    }
}

// ---------------- main: one block per 32-node bin ---------------------------
__global__ __launch_bounds__(256, 4) void bconv_bin32(
    const float* __restrict__ x_j, const short* __restrict__ wbf,
    const int* __restrict__ keybase, const uint2* __restrict__ packed,
    float* __restrict__ out, int N)
{
    __shared__ float acc[BINSZ][33];              // stride 33: conflict-free
    __shared__ unsigned short cls[CAP], tmp[CAP];
    __shared__ int ccnt[9], coff[9], tcum[10];

    int t = threadIdx.x;
    int bin = blockIdx.x;
    int wid = t >> 6, lane = t & 63;
    int row16 = lane & 15, hi = lane >> 4;

    for (int i = t; i < BINSZ * 33; i += 256) (&acc[0][0])[i] = 0.f;

    int s0 = keybase[bin], s1 = keybase[bin + 1];
    const float4* x4 = reinterpret_cast<const float4*>(x_j);
    const unsigned* px = reinterpret_cast<const unsigned*>(packed);

    for (int chunk = s0; chunk < s1; chunk += CAP) {
        __syncthreads();                          // waves done with prev cls
        int clen = min(CAP, s1 - chunk);
        if (t < 9) ccnt[t] = 0;
        __syncthreads();
        for (int i = t; i < clen; i += 256) {
            unsigned rx = px[2 * (chunk + i)];
            int c = (rx >> 24) & 15;
            int r = atomicAdd(&ccnt[c], 1);
            tmp[i] = (unsigned short)((c << 11) | r);
        }
        __syncthreads();
        if (t == 0) {
            int off = 0, tc = 0;
            #pragma unroll
            for (int c = 0; c < 9; ++c) {
                coff[c] = off; tcum[c] = tc;
                off += ccnt[c];
                tc  += (ccnt[c] + 15) >> 4;
            }
            tcum[9] = tc;
        }
        __syncthreads();
        for (int i = t; i < clen; i += 256) {
            unsigned u = tmp[i];
            cls[coff[u >> 11] + (u & 2047)] = (unsigned short)i;
        }
        __syncthreads();
        int ntile = tcum[9];

        auto resolve = [&](int tau, int& c, int& p, float& vm) {
            c = 0;
            #pragma unroll
            for (int q = 1; q < 9; ++q) c += (tau >= tcum[q]) ? 1 : 0;
            int pos = (tau - tcum[c]) * 16 + row16;
            int cc = ccnt[c];
            vm = (pos < cc) ? 1.f : 0.f;
            int idx = cls[coff[c] + min(pos, cc - 1)];
            p = chunk + idx;
        };

        int tau = wid;
        int c0 = 0, p0 = 0; float v0m = 0.f;
        uint2 rec0 = {0, 0}; float4 fA = {0,0,0,0}, fB = {0,0,0,0};
        if (tau < ntile) {
            resolve(tau, c0, p0, v0m);
            rec0 = packed[p0];
            int src = rec0.x & 0xFFFF;
            fA = x4[src * 8 + 2 * hi];
            fB = x4[src * 8 + 2 * hi + 1];
        }
        int cprev = -1;
        short8 w0[4], w1[4];
        for (; tau < ntile; tau += 4) {
            // prefetch next tile's record
            int c1 = c0, p1 = p0; float v1m = 0.f;
            uint2 rec1 = rec0;
            bool hn = (tau + 4) < ntile;
            if (hn) { resolve(tau + 4, c1, p1, v1m); rec1 = packed[p1]; }

            int kx0 = c0 / 3, ky0 = c0 - 3 * (c0 / 3);
            if (c0 != cprev) {                    // wave-uniform branch
                #pragma unroll
                for (int kk = 0; kk < 4; ++kk) {
                    int ks = (kx0 + (kk >> 1)) * NB + (ky0 + (kk & 1));
                    w0[kk] = *reinterpret_cast<const short8*>(
                        wbf + (((ks * 4 + hi) * 2 + 0) * 16 + row16) * 8);
                    w1[kk] = *reinterpret_cast<const short8*>(
                        wbf + (((ks * 4 + hi) * 2 + 1) * 16 + row16) * 8);
                }
                cprev = c0;
            }

            float tx = (float)(rec0.y & 0xFFFF) * (1.f / 21845.f);
            float ty = (float)(rec0.y >> 16)    * (1.f / 21845.f);
            float fx = tx - (float)kx0, fy = ty - (float)ky0;
            float bx0 = (1.f - fx) * v0m, bx1 = fx * v0m;
            float by0 = 1.f - fy,          by1 = fy;
            float bc[4] = { bx0 * by0, bx0 * by1, bx1 * by0, bx1 * by1 };
            int dstloc = (rec0.x >> 16) & (BINSZ - 1);
            float fl[8] = { fA.x, fA.y, fA.z, fA.w, fB.x, fB.y, fB.z, fB.w };

            f32x4 a0 = {0,0,0,0}, a1 = {0,0,0,0};
            #pragma unroll
            for (int kk = 0; kk < 4; ++kk) {
                float s = bc[kk];
                uint4v u;
                u[0] = pk2(fl[0] * s, fl[1] * s);
                u[1] = pk2(fl[2] * s, fl[3] * s);
                u[2] = pk2(fl[4] * s, fl[5] * s);
                u[3] = pk2(fl[6] * s, fl[7] * s);
                short8 av = __builtin_bit_cast(short8, u);
                a0 = __builtin_amdgcn_mfma_f32_16x16x32_bf16(av, w0[kk], a0, 0, 0, 0);
                a1 = __builtin_amdgcn_mfma_f32_16x16x32_bf16(av, w1[kk], a1, 0, 0, 0);
            }
            #pragma unroll
            for (int r = 0; r < 4; ++r) {
                int n = __shfl(dstloc, 4 * hi + r, 64);
                atomicAdd(&acc[n][row16],      a0[r]);
                atomicAdd(&acc[n][16 + row16], a1[r]);
            }
            // gather next tile's features (rec1 already in flight/arrived)
            if (hn) {
                int src = rec1.x & 0xFFFF;
                fA = x4[src * 8 + 2 * hi];
                fB = x4[src * 8 + 2 * hi + 1];
            }
            rec0 = rec1; c0 = c1; p0 = p1; v0m = v1m;
        }
    }
    __syncthreads();

    // writeout: 32 nodes x 32 cols, coalesced, non-atomic
    int nloc = t >> 3, c4 = (t & 7) * 4;
    int node = bin * BINSZ + nloc;
    if (node < N) {
        float4 v;
        v.x = acc[nloc][c4];     v.y = acc[nloc][c4 + 1];
        v.z = acc[nloc][c4 + 2]; v.w = acc[nloc][c4 + 3];
        *reinterpret_cast<float4*>(&out[(size_t)node * F + c4]) = v;
    }
}

// ---------------- fallback (no workspace): f32 VALU path --------------------
__global__ __launch_bounds__(256) void bconv_fallback(
    const float* __restrict__ x_j, const int* __restrict__ ei,
    const float* __restrict__ attr, const float* __restrict__ weight,
    float* __restrict__ out, int E)
{
    __shared__ float wl[16 * F * F];
    __shared__ float featl[8][F];
    for (int idx = threadIdx.x; idx < 4096; idx += 256)
        reinterpret_cast<float4*>(wl)[idx] = reinterpret_cast<const float4*>(weight)[idx];
    __syncthreads();

    int lane = threadIdx.x & 31, eslot = threadIdx.x >> 5;
    for (int p = blockIdx.x * 8 + eslot; p < E; p += gridDim.x * 8) {
        int dst = ei[p], srcn = ei[E + p];
        float ax = attr[2 * p], ay = attr[2 * p + 1];
        featl[eslot][lane] = x_j[(size_t)srcn * F + lane];
        float tx = (ax + 1.0f) * 1.5f, ty = (ay + 1.0f) * 1.5f;
        int kx0 = (int)tx; if (kx0 > 2) kx0 = 2; if (kx0 < 0) kx0 = 0;
        int ky0 = (int)ty; if (ky0 > 2) ky0 = 2; if (ky0 < 0) ky0 = 0;
        float fx = tx - kx0, fy = ty - ky0;
        float bcv[4] = { (1.0f - fx) * (1.0f - fy), (1.0f - fx) * fy,
                         fx * (1.0f - fy), fx * fy };
        float msg = 0.f;
        const float4* f4 = reinterpret_cast<const float4*>(&featl[eslot][0]);
        #pragma unroll
        for (int kk = 0; kk < 4; ++kk) {
            int k = (kx0 + (kk >> 1)) * NB + (ky0 + (kk & 1));
            const float* wk = wl + k * F * F;
            float a2 = 0.f;
            #pragma unroll
            for (int j = 0; j < 8; ++j) {
                float4 f = f4[j];
                a2 = fmaf(f.x, wk[(4 * j + 0) * F + lane], a2);
                a2 = fmaf(f.y, wk[(4 * j + 1) * F + lane], a2);
                a2 = fmaf(f.z, wk[(4 * j + 2) * F + lane], a2);
                a2 = fmaf(f.w, wk[(4 * j + 3) * F + lane], a2);
            }
            msg = fmaf(bcv[kk], a2, msg);
        }
        atomicAdd(&out[(size_t)dst * F + lane], msg);
    }
}

extern "C" void kernel_launch(void* const* d_in, const int* in_sizes, int n_in,
                              void* d_out, int out_size, void* d_ws, size_t ws_size,
                              hipStream_t stream) {
    const float* x_j    = (const float*)d_in[1];
    const int*   ei     = (const int*)d_in[2];
    const float* attr   = (const float*)d_in[3];
    const float* weight = (const float*)d_in[4];
    float* out = (float*)d_out;
    int E = in_sizes[2] / 2;
    int N = in_sizes[0] / F;

    int nbin = (N + BINSZ - 1) >> BINSH;
    // ws ints: keycnt[nbin] | keybase[nbin+1] | cursor[nbin] | wbf(8192) | packed[E]*2
    int off_wbf = ((3 * nbin + 2) + 3) & ~3;
    int off_pk  = (off_wbf + 8192 + 1) & ~1;
    size_t need = ((size_t)off_pk + 2 * (size_t)E) * sizeof(int);

    if (nbin <= MAXBIN && N <= 65536 && ws_size >= need) {
        int* ws      = (int*)d_ws;
        int* keycnt  = ws;
        int* keybase = ws + nbin;
        int* cursor  = ws + 2 * nbin + 1;
        short* wbf   = (short*)(ws + off_wbf);
        uint2* packed = (uint2*)(ws + off_pk);
        hipMemsetAsync(keycnt, 0, (size_t)nbin * sizeof(int), stream);
        w_prep<<<64, 256, 0, stream>>>(weight, wbf);
        k_hist<<<64, 256, 0, stream>>>(ei, E, nbin, keycnt);
        k_scan<<<1, 256, 0, stream>>>(keycnt, keybase, cursor, nbin);
        k_scatter<<<(E + SCH - 1) / SCH, 256, 0, stream>>>(ei, attr, E, nbin, cursor, packed);
        bconv_bin32<<<nbin, 256, 0, stream>>>(x_j, wbf, keybase, packed, out, N);
    } else {
        hipMemsetAsync(d_out, 0, (size_t)out_size * sizeof(float), stream);
        bconv_fallback<<<2048, 256, 0, stream>>>(x_j, ei, attr, weight, out, E);
    }
}